// Round 1
// baseline (280.267 us; speedup 1.0000x reference)
//
#include <hip/hip_runtime.h>
#include <hip/hip_bf16.h>

#define BATCH 16
#define NN    1024
#define DD    128
#define TILE  128
#define PITCH 136   // bf16 elems per LDS row: 128 + 8 pad (16B-aligned, conflict-optimal)

typedef __bf16 bf16_t;
typedef bf16_t bf16x8 __attribute__((ext_vector_type(8)));
typedef float  f32x4  __attribute__((ext_vector_type(4)));

// ws layout (floats):
// [0] coord_sum  [1] reg_sum  [2] count_loss_sum  [3] bce_sum
// [4+b] pos_sum  [20+b] pos_cnt  [36+b] neg_sum  [52+b] neg_cnt   (b<16) -> 68 floats

__global__ __launch_bounds__(256) void small_losses(
    const float* __restrict__ pcoord, const float* __restrict__ pts,
    const float* __restrict__ masks,  const float* __restrict__ pcount,
    const float* __restrict__ nf, float* __restrict__ ws) {
  __shared__ float sh[4][3];
  float reg = 0.f, coord = 0.f, cnt = 0.f;

  const int gt = blockIdx.x * 256 + threadIdx.x;
  const int stride = 256 * 256;

  // reg: node_features, 2097152 floats = 524288 float4
  const float4* nf4 = (const float4*)nf;
  for (int i = gt; i < 524288; i += stride) {
    float4 v = nf4[i];
    reg += v.x*v.x + v.y*v.y + v.z*v.z + v.w*v.w;
  }
  // coord: 32768 floats = 8192 float4
  const float4* a4 = (const float4*)pcoord;
  const float4* b4 = (const float4*)pts;
  for (int i = gt; i < 8192; i += stride) {
    float4 a = a4[i], b = b4[i];
    float dx = a.x-b.x, dy = a.y-b.y, dz = a.z-b.z, dw = a.w-b.w;
    coord += dx*dx + dy*dy + dz*dz + dw*dw;
  }
  // count: blocks 0..15 each sum masks of one batch
  if (blockIdx.x < 16) {
    const float* m = masks + blockIdx.x * NN;
    for (int i = threadIdx.x; i < NN; i += 256) cnt += m[i];
  }

  const int lane = threadIdx.x & 63, w = threadIdx.x >> 6;
  #pragma unroll
  for (int o = 32; o; o >>= 1) {
    coord += __shfl_xor(coord, o);
    reg   += __shfl_xor(reg, o);
    cnt   += __shfl_xor(cnt, o);
  }
  if (lane == 0) { sh[w][0] = coord; sh[w][1] = reg; sh[w][2] = cnt; }
  __syncthreads();
  if (threadIdx.x == 0) {
    float c = 0.f, r = 0.f, n = 0.f;
    for (int i = 0; i < 4; ++i) { c += sh[i][0]; r += sh[i][1]; n += sh[i][2]; }
    atomicAdd(&ws[0], c);
    atomicAdd(&ws[1], r);
    if (blockIdx.x < 16) {
      float d = fabsf(pcount[blockIdx.x] - n);
      float term = (d < 1.f) ? 0.5f * d * d : d - 0.5f;
      atomicAdd(&ws[2], term);
    }
  }
}

__global__ __launch_bounds__(256, 2) void fused_gram_bce(
    const float* __restrict__ logits, const float* __restrict__ adj,
    const float* __restrict__ feat, float* __restrict__ ws) {
  __shared__ __align__(16) bf16_t lsA[TILE * PITCH];
  __shared__ __align__(16) bf16_t lsB[TILE * PITCH];
  __shared__ float nrmA[TILE];
  __shared__ float nrmB[TILE];
  __shared__ float red[4][5];

  const int bx  = blockIdx.x;
  const int b   = bx >> 6;            // 64 tiles per batch
  const int tid = bx & 63;
  const int ti  = (tid >> 3) << 7;    // tile row base
  const int tj  = (tid & 7)  << 7;    // tile col base

  const int t = threadIdx.x;
  const float* fb = feat + (size_t)b * NN * DD;

  // ---- stage both 128x128 feature tiles (fp32 -> bf16) into LDS ----
  #pragma unroll
  for (int it = 0; it < 16; ++it) {
    int cid  = it * 256 + t;          // 0..4095 chunks of 8 floats
    int tile = cid >> 11;
    int sub  = cid & 2047;
    int row  = sub >> 4;
    int c8   = sub & 15;
    const float* src = fb + (size_t)((tile ? tj : ti) + row) * DD + c8 * 8;
    float4 u = *(const float4*)src;
    float4 v = *(const float4*)(src + 4);
    bf16_t* dst = (tile ? lsB : lsA) + row * PITCH + c8 * 8;
    dst[0] = (bf16_t)u.x; dst[1] = (bf16_t)u.y; dst[2] = (bf16_t)u.z; dst[3] = (bf16_t)u.w;
    dst[4] = (bf16_t)v.x; dst[5] = (bf16_t)v.y; dst[6] = (bf16_t)v.z; dst[7] = (bf16_t)v.w;
  }
  __syncthreads();

  // ---- per-row squared norms from the bf16 data (consistent with MFMA dot) ----
  {
    int row = t & 127;
    const bf16_t* src = (t < 128 ? lsA : lsB) + row * PITCH;
    float s = 0.f;
    #pragma unroll
    for (int c = 0; c < 16; ++c) {
      bf16x8 ch = *(const bf16x8*)(src + c * 8);
      #pragma unroll
      for (int i = 0; i < 8; ++i) { float v = (float)ch[i]; s += v * v; }
    }
    if (t < 128) nrmA[row] = s; else nrmB[row] = s;
  }
  __syncthreads();

  // ---- MFMA Gram: wave w computes rows [w*32, w*32+32) x all 128 cols ----
  const int lane = t & 63;
  const int wave = t >> 6;
  const int lrow = lane & 15;
  const int quad = lane >> 4;

  f32x4 acc[2][8];
  #pragma unroll
  for (int fr = 0; fr < 2; ++fr)
    #pragma unroll
    for (int fc = 0; fc < 8; ++fc)
      acc[fr][fc] = (f32x4){0.f, 0.f, 0.f, 0.f};

  #pragma unroll
  for (int k0 = 0; k0 < DD; k0 += 32) {
    const int kc = k0 + quad * 8;
    bf16x8 aF0 = *(const bf16x8*)&lsA[(wave * 32 + 0  + lrow) * PITCH + kc];
    bf16x8 aF1 = *(const bf16x8*)&lsA[(wave * 32 + 16 + lrow) * PITCH + kc];
    bf16x8 bF[8];
    #pragma unroll
    for (int fc = 0; fc < 8; ++fc)
      bF[fc] = *(const bf16x8*)&lsB[(fc * 16 + lrow) * PITCH + kc];
    #pragma unroll
    for (int fc = 0; fc < 8; ++fc) {
      acc[0][fc] = __builtin_amdgcn_mfma_f32_16x16x32_bf16(aF0, bF[fc], acc[0][fc], 0, 0, 0);
      acc[1][fc] = __builtin_amdgcn_mfma_f32_16x16x32_bf16(aF1, bF[fc], acc[1][fc], 0, 0, 0);
    }
  }

  // ---- fused epilogue: BCE + contrastive pos/neg, one read of logits/adj ----
  float bsum = 0.f, poss = 0.f, posc = 0.f, negs = 0.f, negc = 0.f;
  const size_t base = (size_t)b * NN * NN;
  #pragma unroll
  for (int fr = 0; fr < 2; ++fr) {
    const int rbase = wave * 32 + fr * 16 + quad * 4;
    #pragma unroll
    for (int fc = 0; fc < 8; ++fc) {
      const int ctile = fc * 16 + lrow;
      const int gcol  = tj + ctile;
      const float ncol = nrmB[ctile];
      #pragma unroll
      for (int r = 0; r < 4; ++r) {
        const int rtile = rbase + r;
        const int grow  = ti + rtile;
        const size_t idx = base + (size_t)grow * NN + gcol;
        float l  = logits[idx];
        float tv = adj[idx];
        bsum += fmaxf(l, 0.f) - l * tv + log1pf(__expf(-fabsf(l)));
        float sq = fmaxf(nrmA[rtile] + ncol - 2.f * acc[fr][fc][r], 0.f);
        if (tv > 0.5f) {
          poss += sq; posc += 1.f;
        } else if (grow != gcol) {
          negc += 1.f;
          if (sq < 1.f) {
            float d = sqrtf(fmaxf(sq, 1e-12f));
            float h = 1.f - d;
            negs += h * h;
          }
        }
      }
    }
  }

  #pragma unroll
  for (int o = 32; o; o >>= 1) {
    bsum += __shfl_xor(bsum, o);
    poss += __shfl_xor(poss, o);
    posc += __shfl_xor(posc, o);
    negs += __shfl_xor(negs, o);
    negc += __shfl_xor(negc, o);
  }
  if (lane == 0) {
    red[wave][0] = bsum; red[wave][1] = poss; red[wave][2] = posc;
    red[wave][3] = negs; red[wave][4] = negc;
  }
  __syncthreads();
  if (t == 0) {
    float s0 = 0.f, s1 = 0.f, s2 = 0.f, s3 = 0.f, s4 = 0.f;
    for (int w = 0; w < 4; ++w) {
      s0 += red[w][0]; s1 += red[w][1]; s2 += red[w][2];
      s3 += red[w][3]; s4 += red[w][4];
    }
    atomicAdd(&ws[3], s0);
    atomicAdd(&ws[4 + b], s1);
    atomicAdd(&ws[20 + b], s2);
    atomicAdd(&ws[36 + b], s3);
    atomicAdd(&ws[52 + b], s4);
  }
}

__global__ void finalize(const float* __restrict__ ws, float* __restrict__ out) {
  if (threadIdx.x != 0 || blockIdx.x != 0) return;
  float coord = ws[0] / 32768.f;
  float reg   = ws[1] / 2097152.f;
  float cntl  = ws[2] / 16.f;
  float edge  = ws[3] / 16777216.f;
  float contra = 0.f;
  for (int b = 0; b < 16; ++b) {
    float p = ws[4 + b]  / fmaxf(ws[20 + b], 1.f);
    float n = ws[36 + b] / fmaxf(ws[52 + b], 1.f);
    contra += p + n;
  }
  contra *= (1.f / 16.f);
  float total = coord + 2.f * edge + 0.1f * cntl + 0.001f * reg + 0.1f * contra;
  out[0] = total; out[1] = coord; out[2] = edge;
  out[3] = cntl;  out[4] = reg;   out[5] = contra;
}

extern "C" void kernel_launch(void* const* d_in, const int* in_sizes, int n_in,
                              void* d_out, int out_size, void* d_ws, size_t ws_size,
                              hipStream_t stream) {
  (void)in_sizes; (void)n_in; (void)out_size; (void)ws_size;
  const float* pcoord = (const float*)d_in[0];
  const float* pts    = (const float*)d_in[1];
  const float* logits = (const float*)d_in[2];
  const float* adj    = (const float*)d_in[3];
  const float* masks  = (const float*)d_in[4];
  const float* pcount = (const float*)d_in[5];
  const float* nf     = (const float*)d_in[6];
  float* ws  = (float*)d_ws;
  float* out = (float*)d_out;

  hipMemsetAsync(ws, 0, 68 * sizeof(float), stream);
  small_losses<<<256, 256, 0, stream>>>(pcoord, pts, masks, pcount, nf, ws);
  fused_gram_bce<<<1024, 256, 0, stream>>>(logits, adj, nf, ws);
  finalize<<<1, 64, 0, stream>>>(ws, out);
}

// Round 2
// 241.630 us; speedup vs baseline: 1.1599x; 1.1599x over previous
//
#include <hip/hip_runtime.h>
#include <hip/hip_bf16.h>

#define NN    1024
#define DD    128
#define TILE  128
#define PITCH 136   // bf16 elems per LDS tile row: 128 + 8 pad (16B-aligned, MFMA-frag conflict-free)
#define SQP   132   // f32 elems per LDS sq row: 128 + 4 pad (16B-aligned, frag-write conflict-free)

typedef __bf16 bf16_t;
typedef bf16_t bf16x8 __attribute__((ext_vector_type(8)));
typedef float  f32x4  __attribute__((ext_vector_type(4)));

// ws layout (floats):
// [0] coord_sum  [1] reg_sum  [2] count_loss_sum  [3] bce_sum
// [4+b] pos_sum  [20+b] pos_cnt  [36+b] neg_sum  [52+b] neg_cnt   (b<16) -> 68 floats

__global__ __launch_bounds__(256) void small_losses(
    const float* __restrict__ pcoord, const float* __restrict__ pts,
    const float* __restrict__ masks,  const float* __restrict__ pcount,
    float* __restrict__ ws) {
  // grid = 16 blocks; block b sums masks of batch b; coord spread over all.
  __shared__ float sh[4][2];
  float coord = 0.f, cnt = 0.f;

  const int gt = blockIdx.x * 256 + threadIdx.x;
  const int stride = 16 * 256;

  const float4* a4 = (const float4*)pcoord;
  const float4* b4 = (const float4*)pts;
  for (int i = gt; i < 8192; i += stride) {
    float4 a = a4[i], b = b4[i];
    float dx = a.x-b.x, dy = a.y-b.y, dz = a.z-b.z, dw = a.w-b.w;
    coord += dx*dx + dy*dy + dz*dz + dw*dw;
  }
  const float* m = masks + blockIdx.x * NN;
  for (int i = threadIdx.x; i < NN; i += 256) cnt += m[i];

  const int lane = threadIdx.x & 63, w = threadIdx.x >> 6;
  #pragma unroll
  for (int o = 32; o; o >>= 1) {
    coord += __shfl_xor(coord, o);
    cnt   += __shfl_xor(cnt, o);
  }
  if (lane == 0) { sh[w][0] = coord; sh[w][1] = cnt; }
  __syncthreads();
  if (threadIdx.x == 0) {
    float c = 0.f, n = 0.f;
    for (int i = 0; i < 4; ++i) { c += sh[i][0]; n += sh[i][1]; }
    atomicAdd(&ws[0], c);
    float d = fabsf(pcount[blockIdx.x] - n);
    float term = (d < 1.f) ? 0.5f * d * d : d - 0.5f;
    atomicAdd(&ws[2], term);
  }
}

__device__ __forceinline__ void loss_elem(float l, float a, float s, int grow, int gcol,
    float& bsum, float& poss, float& posc, float& negs, float& negc) {
  bsum += fmaxf(l, 0.f) - l * a + log1pf(__expf(-fabsf(l)));
  if (a > 0.5f) {
    poss += s; posc += 1.f;
  } else if (grow != gcol) {
    negc += 1.f;
    if (s < 1.f) {
      float d = sqrtf(fmaxf(s, 1e-12f));
      float h = 1.f - d;
      negs += h * h;
    }
  }
}

__global__ __launch_bounds__(256, 2) void fused_gram_bce(
    const float* __restrict__ logits, const float* __restrict__ adj,
    const float* __restrict__ feat, float* __restrict__ ws) {
  // tiles (2*128*136*2 = 69632 B) and sq buffer (128*132*4 = 67584 B) overlap:
  __shared__ __align__(16) char smem[2 * TILE * PITCH * sizeof(bf16_t)];
  bf16_t* lsA = (bf16_t*)smem;
  bf16_t* lsB = (bf16_t*)(smem + TILE * PITCH * sizeof(bf16_t));
  float*  sqb = (float*)smem;
  __shared__ float nrmA[TILE];
  __shared__ float nrmB[TILE];
  __shared__ float red[4][6];

  const int bx  = blockIdx.x;
  const int b   = bx >> 6;            // 64 tiles per batch
  const int tid = bx & 63;
  const int ti  = (tid >> 3) << 7;    // tile row base
  const int tj  = (tid & 7)  << 7;    // tile col base
  const bool diag = (ti == tj);

  const int t = threadIdx.x;
  const float* fb = feat + (size_t)b * NN * DD;

  // ---- stage both 128x128 feature tiles (fp32 -> bf16) into LDS ----
  // Diagonal blocks also accumulate fp32 sum(nf^2) for reg_loss (each batch row
  // is staged as tile-A by exactly one diagonal block -> counted exactly once).
  float regsum = 0.f;
  #pragma unroll
  for (int it = 0; it < 16; ++it) {
    int cid  = it * 256 + t;          // 0..4095 chunks of 8 floats
    int tile = cid >> 11;
    int sub  = cid & 2047;
    int row  = sub >> 4;
    int c8   = sub & 15;
    const float* src = fb + (size_t)((tile ? tj : ti) + row) * DD + c8 * 8;
    float4 u = *(const float4*)src;
    float4 v = *(const float4*)(src + 4);
    if (diag && tile == 0)
      regsum += u.x*u.x + u.y*u.y + u.z*u.z + u.w*u.w
              + v.x*v.x + v.y*v.y + v.z*v.z + v.w*v.w;
    bf16_t* dst = (tile ? lsB : lsA) + row * PITCH + c8 * 8;
    dst[0] = (bf16_t)u.x; dst[1] = (bf16_t)u.y; dst[2] = (bf16_t)u.z; dst[3] = (bf16_t)u.w;
    dst[4] = (bf16_t)v.x; dst[5] = (bf16_t)v.y; dst[6] = (bf16_t)v.z; dst[7] = (bf16_t)v.w;
  }
  __syncthreads();

  // ---- per-row squared norms from the bf16 data (consistent with MFMA dot) ----
  {
    int row = t & 127;
    const bf16_t* src = (t < 128 ? lsA : lsB) + row * PITCH;
    float s = 0.f;
    #pragma unroll
    for (int c = 0; c < 16; ++c) {
      bf16x8 ch = *(const bf16x8*)(src + c * 8);
      #pragma unroll
      for (int i = 0; i < 8; ++i) { float v = (float)ch[i]; s += v * v; }
    }
    if (t < 128) nrmA[row] = s; else nrmB[row] = s;
  }
  __syncthreads();

  // ---- MFMA Gram: wave w computes rows [w*32, w*32+32) x all 128 cols ----
  const int lane = t & 63;
  const int wave = t >> 6;
  const int lrow = lane & 15;
  const int quad = lane >> 4;

  f32x4 acc[2][8];
  #pragma unroll
  for (int fr = 0; fr < 2; ++fr)
    #pragma unroll
    for (int fc = 0; fc < 8; ++fc)
      acc[fr][fc] = (f32x4){0.f, 0.f, 0.f, 0.f};

  #pragma unroll
  for (int k0 = 0; k0 < DD; k0 += 32) {
    const int kc = k0 + quad * 8;
    bf16x8 aF0 = *(const bf16x8*)&lsA[(wave * 32 + 0  + lrow) * PITCH + kc];
    bf16x8 aF1 = *(const bf16x8*)&lsA[(wave * 32 + 16 + lrow) * PITCH + kc];
    bf16x8 bF[8];
    #pragma unroll
    for (int fc = 0; fc < 8; ++fc)
      bF[fc] = *(const bf16x8*)&lsB[(fc * 16 + lrow) * PITCH + kc];
    #pragma unroll
    for (int fc = 0; fc < 8; ++fc) {
      acc[0][fc] = __builtin_amdgcn_mfma_f32_16x16x32_bf16(aF0, bF[fc], acc[0][fc], 0, 0, 0);
      acc[1][fc] = __builtin_amdgcn_mfma_f32_16x16x32_bf16(aF1, bF[fc], acc[1][fc], 0, 0, 0);
    }
  }
  __syncthreads();   // all waves done reading tiles; safe to overwrite with sq

  // ---- dump sq = ||fi||^2 + ||fj||^2 - 2<fi,fj> into LDS (frag layout write) ----
  // pitch 132: rows {q*4+r} shift banks by 4*row -> 64 lanes cover all 32 banks.
  #pragma unroll
  for (int fr = 0; fr < 2; ++fr) {
    const int rbase = wave * 32 + fr * 16 + quad * 4;
    #pragma unroll
    for (int fc = 0; fc < 8; ++fc) {
      const int ctile = fc * 16 + lrow;
      const float ncol = nrmB[ctile];
      #pragma unroll
      for (int r = 0; r < 4; ++r) {
        const int rtile = rbase + r;
        sqb[rtile * SQP + ctile] = fmaxf(nrmA[rtile] + ncol - 2.f * acc[fr][fc][r], 0.f);
      }
    }
  }
  __syncthreads();

  // ---- phase 2: coalesced sweep of the tile. float4 global loads, sq from LDS ----
  float bsum = 0.f, poss = 0.f, posc = 0.f, negs = 0.f, negc = 0.f;
  const size_t base = (size_t)b * NN * NN;
  #pragma unroll
  for (int it = 0; it < 16; ++it) {
    int cid = it * 256 + t;           // 0..4095 float4 chunks
    int row = cid >> 5;               // 0..127
    int c4  = cid & 31;               // 0..31
    const int grow = ti + row;
    const int gc0  = tj + c4 * 4;
    const size_t gidx = base + (size_t)grow * NN + gc0;
    float4 l = *(const float4*)(logits + gidx);
    float4 a = *(const float4*)(adj + gidx);
    float4 s = *(const float4*)&sqb[row * SQP + c4 * 4];
    loss_elem(l.x, a.x, s.x, grow, gc0 + 0, bsum, poss, posc, negs, negc);
    loss_elem(l.y, a.y, s.y, grow, gc0 + 1, bsum, poss, posc, negs, negc);
    loss_elem(l.z, a.z, s.z, grow, gc0 + 2, bsum, poss, posc, negs, negc);
    loss_elem(l.w, a.w, s.w, grow, gc0 + 3, bsum, poss, posc, negs, negc);
  }

  #pragma unroll
  for (int o = 32; o; o >>= 1) {
    bsum   += __shfl_xor(bsum, o);
    poss   += __shfl_xor(poss, o);
    posc   += __shfl_xor(posc, o);
    negs   += __shfl_xor(negs, o);
    negc   += __shfl_xor(negc, o);
    regsum += __shfl_xor(regsum, o);
  }
  if (lane == 0) {
    red[wave][0] = bsum; red[wave][1] = poss; red[wave][2] = posc;
    red[wave][3] = negs; red[wave][4] = negc; red[wave][5] = regsum;
  }
  __syncthreads();
  if (t == 0) {
    float s0 = 0.f, s1 = 0.f, s2 = 0.f, s3 = 0.f, s4 = 0.f, s5 = 0.f;
    for (int w = 0; w < 4; ++w) {
      s0 += red[w][0]; s1 += red[w][1]; s2 += red[w][2];
      s3 += red[w][3]; s4 += red[w][4]; s5 += red[w][5];
    }
    atomicAdd(&ws[3], s0);
    atomicAdd(&ws[4 + b], s1);
    atomicAdd(&ws[20 + b], s2);
    atomicAdd(&ws[36 + b], s3);
    atomicAdd(&ws[52 + b], s4);
    if (diag) atomicAdd(&ws[1], s5);
  }
}

__global__ void finalize(const float* __restrict__ ws, float* __restrict__ out) {
  if (threadIdx.x != 0 || blockIdx.x != 0) return;
  float coord = ws[0] / 32768.f;
  float reg   = ws[1] / 2097152.f;
  float cntl  = ws[2] / 16.f;
  float edge  = ws[3] / 16777216.f;
  float contra = 0.f;
  for (int b = 0; b < 16; ++b) {
    float p = ws[4 + b]  / fmaxf(ws[20 + b], 1.f);
    float n = ws[36 + b] / fmaxf(ws[52 + b], 1.f);
    contra += p + n;
  }
  contra *= (1.f / 16.f);
  float total = coord + 2.f * edge + 0.1f * cntl + 0.001f * reg + 0.1f * contra;
  out[0] = total; out[1] = coord; out[2] = edge;
  out[3] = cntl;  out[4] = reg;   out[5] = contra;
}

extern "C" void kernel_launch(void* const* d_in, const int* in_sizes, int n_in,
                              void* d_out, int out_size, void* d_ws, size_t ws_size,
                              hipStream_t stream) {
  (void)in_sizes; (void)n_in; (void)out_size; (void)ws_size;
  const float* pcoord = (const float*)d_in[0];
  const float* pts    = (const float*)d_in[1];
  const float* logits = (const float*)d_in[2];
  const float* adj    = (const float*)d_in[3];
  const float* masks  = (const float*)d_in[4];
  const float* pcount = (const float*)d_in[5];
  const float* nf     = (const float*)d_in[6];
  float* ws  = (float*)d_ws;
  float* out = (float*)d_out;

  hipMemsetAsync(ws, 0, 68 * sizeof(float), stream);
  small_losses<<<16, 256, 0, stream>>>(pcoord, pts, masks, pcount, ws);
  fused_gram_bce<<<1024, 256, 0, stream>>>(logits, adj, nf, ws);
  finalize<<<1, 64, 0, stream>>>(ws, out);
}

// Round 3
// 200.556 us; speedup vs baseline: 1.3975x; 1.2048x over previous
//
#include <hip/hip_runtime.h>
#include <hip/hip_bf16.h>

#define NN    1024
#define DD    128
#define TILE  128
#define PITCH 136   // bf16 elems per LDS tile row: 128 + 8 pad (16B-aligned, MFMA-frag conflict-free)
#define SQP   132   // f32 elems per LDS sq row: 128 + 4 pad (16B-aligned, frag-write conflict-free)

typedef __bf16 bf16_t;
typedef bf16_t bf16x8 __attribute__((ext_vector_type(8)));
typedef float  f32x4  __attribute__((ext_vector_type(4)));

// ws layout (floats):
// [0] coord_sum  [1] reg_sum  [2] count_loss_sum  [3] bce_sum
// [4+b] pos_sum  [20+b] pos_cnt  [36+b] neg_sum  [52+b] neg_cnt   (b<16) -> 68 floats

__global__ __launch_bounds__(256) void small_losses(
    const float* __restrict__ pcoord, const float* __restrict__ pts,
    const float* __restrict__ masks,  const float* __restrict__ pcount,
    float* __restrict__ ws) {
  __shared__ float sh[4][2];
  float coord = 0.f, cnt = 0.f;

  const int gt = blockIdx.x * 256 + threadIdx.x;
  const int stride = 16 * 256;

  const float4* a4 = (const float4*)pcoord;
  const float4* b4 = (const float4*)pts;
  for (int i = gt; i < 8192; i += stride) {
    float4 a = a4[i], b = b4[i];
    float dx = a.x-b.x, dy = a.y-b.y, dz = a.z-b.z, dw = a.w-b.w;
    coord += dx*dx + dy*dy + dz*dz + dw*dw;
  }
  const float* m = masks + blockIdx.x * NN;
  for (int i = threadIdx.x; i < NN; i += 256) cnt += m[i];

  const int lane = threadIdx.x & 63, w = threadIdx.x >> 6;
  #pragma unroll
  for (int o = 32; o; o >>= 1) {
    coord += __shfl_xor(coord, o);
    cnt   += __shfl_xor(cnt, o);
  }
  if (lane == 0) { sh[w][0] = coord; sh[w][1] = cnt; }
  __syncthreads();
  if (threadIdx.x == 0) {
    float c = 0.f, n = 0.f;
    for (int i = 0; i < 4; ++i) { c += sh[i][0]; n += sh[i][1]; }
    atomicAdd(&ws[0], c);
    float d = fabsf(pcount[blockIdx.x] - n);
    float term = (d < 1.f) ? 0.5f * d * d : d - 0.5f;
    atomicAdd(&ws[2], term);
  }
}

__device__ __forceinline__ void loss_elem(float l, float a, float s, int grow, int gcol,
    float& bsum, float& poss, float& posc, float& negs, float& negc) {
  // softplus(-|l|) via HW exp/log: ~1e-7 abs error, fine at this threshold
  bsum += fmaxf(l, 0.f) - l * a + __logf(1.f + __expf(-fabsf(l)));
  if (a > 0.5f) {
    poss += s; posc += 1.f;
  } else if (grow != gcol) {
    negc += 1.f;
    if (s < 1.f) {                       // rare for random 128-d features
      float d = sqrtf(fmaxf(s, 1e-12f));
      float h = 1.f - d;
      negs += h * h;
    }
  }
}

__global__ __launch_bounds__(512, 4) void fused_gram_bce(
    const float* __restrict__ logits, const float* __restrict__ adj,
    const float* __restrict__ feat, float* __restrict__ ws) {
  // tiles (2*128*136*2 = 69632 B) and sq buffer (128*132*4 = 67584 B) overlap:
  __shared__ __align__(16) char smem[2 * TILE * PITCH * sizeof(bf16_t)];
  bf16_t* lsA = (bf16_t*)smem;
  bf16_t* lsB = (bf16_t*)(smem + TILE * PITCH * sizeof(bf16_t));
  float*  sqb = (float*)smem;
  __shared__ float nrmA[TILE];
  __shared__ float nrmB[TILE];
  __shared__ float red[8][6];

  const int bx  = blockIdx.x;
  const int b   = bx >> 6;            // 64 tiles per batch
  const int tid = bx & 63;
  const int ti  = (tid >> 3) << 7;    // tile row base
  const int tj  = (tid & 7)  << 7;    // tile col base
  const bool diag = (ti == tj);

  const int t = threadIdx.x;          // 0..511, 8 waves
  const float* fb = feat + (size_t)b * NN * DD;

  // ---- stage both 128x128 feature tiles (fp32 -> bf16) into LDS ----
  // Diagonal blocks also accumulate fp32 sum(nf^2) for reg_loss (each batch row
  // is staged as tile-A by exactly one diagonal block -> counted exactly once).
  float regsum = 0.f;
  #pragma unroll
  for (int it = 0; it < 8; ++it) {
    int cid  = it * 512 + t;          // 0..4095 chunks of 8 floats
    int tile = cid >> 11;
    int sub  = cid & 2047;
    int row  = sub >> 4;
    int c8   = sub & 15;
    const float* src = fb + (size_t)((tile ? tj : ti) + row) * DD + c8 * 8;
    float4 u = *(const float4*)src;
    float4 v = *(const float4*)(src + 4);
    if (diag && tile == 0)
      regsum += u.x*u.x + u.y*u.y + u.z*u.z + u.w*u.w
              + v.x*v.x + v.y*v.y + v.z*v.z + v.w*v.w;
    bf16_t* dst = (tile ? lsB : lsA) + row * PITCH + c8 * 8;
    dst[0] = (bf16_t)u.x; dst[1] = (bf16_t)u.y; dst[2] = (bf16_t)u.z; dst[3] = (bf16_t)u.w;
    dst[4] = (bf16_t)v.x; dst[5] = (bf16_t)v.y; dst[6] = (bf16_t)v.z; dst[7] = (bf16_t)v.w;
  }
  __syncthreads();

  // ---- per-row squared norms from the bf16 data (consistent with MFMA dot) ----
  // 512 threads, 256 rows: pair (2r, 2r+1) splits a row in halves, shfl-combine.
  {
    int row  = t >> 1;                // 0..255
    int half = t & 1;
    const bf16_t* src = (row < 128 ? lsA + row * PITCH : lsB + (row - 128) * PITCH)
                        + half * 64;
    float s = 0.f;
    #pragma unroll
    for (int c = 0; c < 8; ++c) {
      bf16x8 ch = *(const bf16x8*)(src + c * 8);
      #pragma unroll
      for (int i = 0; i < 8; ++i) { float v = (float)ch[i]; s += v * v; }
    }
    s += __shfl_xor(s, 1);
    if (half == 0) {
      if (row < 128) nrmA[row] = s; else nrmB[row - 128] = s;
    }
  }
  __syncthreads();

  // ---- MFMA Gram: wave w computes rows [w*16, w*16+16) x all 128 cols ----
  const int lane = t & 63;
  const int wave = t >> 6;            // 0..7
  const int lrow = lane & 15;
  const int quad = lane >> 4;

  f32x4 acc[8];
  #pragma unroll
  for (int fc = 0; fc < 8; ++fc) acc[fc] = (f32x4){0.f, 0.f, 0.f, 0.f};

  #pragma unroll
  for (int k0 = 0; k0 < DD; k0 += 32) {
    const int kc = k0 + quad * 8;
    bf16x8 aF = *(const bf16x8*)&lsA[(wave * 16 + lrow) * PITCH + kc];
    bf16x8 bF[8];
    #pragma unroll
    for (int fc = 0; fc < 8; ++fc)
      bF[fc] = *(const bf16x8*)&lsB[(fc * 16 + lrow) * PITCH + kc];
    #pragma unroll
    for (int fc = 0; fc < 8; ++fc)
      acc[fc] = __builtin_amdgcn_mfma_f32_16x16x32_bf16(aF, bF[fc], acc[fc], 0, 0, 0);
  }
  __syncthreads();   // all waves done reading tiles; safe to overwrite with sq

  // ---- dump sq = ||fi||^2 + ||fj||^2 - 2<fi,fj> into LDS (frag layout write) ----
  {
    const int rbase = wave * 16 + quad * 4;
    #pragma unroll
    for (int fc = 0; fc < 8; ++fc) {
      const int ctile = fc * 16 + lrow;
      const float ncol = nrmB[ctile];
      #pragma unroll
      for (int r = 0; r < 4; ++r) {
        const int rtile = rbase + r;
        sqb[rtile * SQP + ctile] = fmaxf(nrmA[rtile] + ncol - 2.f * acc[fc][r], 0.f);
      }
    }
  }
  __syncthreads();

  // ---- phase 2: coalesced sweep. float4 global loads (depth-2 pipeline) ----
  float bsum = 0.f, poss = 0.f, posc = 0.f, negs = 0.f, negc = 0.f;
  const size_t base = (size_t)b * NN * NN;
  const int c4 = t & 31, r0 = t >> 5;       // 32 threads/row, 16 rows/iter
  const int gcol0 = tj + c4 * 4;
  const float* lp = logits + base + (size_t)(ti + r0) * NN + gcol0;
  const float* ap = adj    + base + (size_t)(ti + r0) * NN + gcol0;

  float4 l0 = *(const float4*)lp;
  float4 a0 = *(const float4*)ap;
  #pragma unroll
  for (int it = 0; it < 8; ++it) {
    float4 l = l0, a = a0;
    if (it < 7) {
      l0 = *(const float4*)(lp + (size_t)(it + 1) * 16 * NN);
      a0 = *(const float4*)(ap + (size_t)(it + 1) * 16 * NN);
    }
    const int row  = it * 16 + r0;
    const int grow = ti + row;
    float4 s = *(const float4*)&sqb[row * SQP + c4 * 4];
    loss_elem(l.x, a.x, s.x, grow, gcol0 + 0, bsum, poss, posc, negs, negc);
    loss_elem(l.y, a.y, s.y, grow, gcol0 + 1, bsum, poss, posc, negs, negc);
    loss_elem(l.z, a.z, s.z, grow, gcol0 + 2, bsum, poss, posc, negs, negc);
    loss_elem(l.w, a.w, s.w, grow, gcol0 + 3, bsum, poss, posc, negs, negc);
  }

  #pragma unroll
  for (int o = 32; o; o >>= 1) {
    bsum   += __shfl_xor(bsum, o);
    poss   += __shfl_xor(poss, o);
    posc   += __shfl_xor(posc, o);
    negs   += __shfl_xor(negs, o);
    negc   += __shfl_xor(negc, o);
    regsum += __shfl_xor(regsum, o);
  }
  if (lane == 0) {
    red[wave][0] = bsum; red[wave][1] = poss; red[wave][2] = posc;
    red[wave][3] = negs; red[wave][4] = negc; red[wave][5] = regsum;
  }
  __syncthreads();
  if (t == 0) {
    float s0 = 0.f, s1 = 0.f, s2 = 0.f, s3 = 0.f, s4 = 0.f, s5 = 0.f;
    for (int w = 0; w < 8; ++w) {
      s0 += red[w][0]; s1 += red[w][1]; s2 += red[w][2];
      s3 += red[w][3]; s4 += red[w][4]; s5 += red[w][5];
    }
    atomicAdd(&ws[3], s0);
    atomicAdd(&ws[4 + b], s1);
    atomicAdd(&ws[20 + b], s2);
    atomicAdd(&ws[36 + b], s3);
    atomicAdd(&ws[52 + b], s4);
    if (diag) atomicAdd(&ws[1], s5);
  }
}

__global__ void finalize(const float* __restrict__ ws, float* __restrict__ out) {
  if (threadIdx.x != 0 || blockIdx.x != 0) return;
  float coord = ws[0] / 32768.f;
  float reg   = ws[1] / 2097152.f;
  float cntl  = ws[2] / 16.f;
  float edge  = ws[3] / 16777216.f;
  float contra = 0.f;
  for (int b = 0; b < 16; ++b) {
    float p = ws[4 + b]  / fmaxf(ws[20 + b], 1.f);
    float n = ws[36 + b] / fmaxf(ws[52 + b], 1.f);
    contra += p + n;
  }
  contra *= (1.f / 16.f);
  float total = coord + 2.f * edge + 0.1f * cntl + 0.001f * reg + 0.1f * contra;
  out[0] = total; out[1] = coord; out[2] = edge;
  out[3] = cntl;  out[4] = reg;   out[5] = contra;
}

extern "C" void kernel_launch(void* const* d_in, const int* in_sizes, int n_in,
                              void* d_out, int out_size, void* d_ws, size_t ws_size,
                              hipStream_t stream) {
  (void)in_sizes; (void)n_in; (void)out_size; (void)ws_size;
  const float* pcoord = (const float*)d_in[0];
  const float* pts    = (const float*)d_in[1];
  const float* logits = (const float*)d_in[2];
  const float* adj    = (const float*)d_in[3];
  const float* masks  = (const float*)d_in[4];
  const float* pcount = (const float*)d_in[5];
  const float* nf     = (const float*)d_in[6];
  float* ws  = (float*)d_ws;
  float* out = (float*)d_out;

  hipMemsetAsync(ws, 0, 68 * sizeof(float), stream);
  small_losses<<<16, 256, 0, stream>>>(pcoord, pts, masks, pcount, ws);
  fused_gram_bce<<<1024, 512, 0, stream>>>(logits, adj, nf, ws);
  finalize<<<1, 64, 0, stream>>>(ws, out);
}